// Round 1
// baseline (137.343 us; speedup 1.0000x reference)
//
#include <hip/hip_runtime.h>
#include <stdint.h>

// BinarizeLinear: out[i][j] = sum_k sign(x[i][k]) * sign(W[j][k]) + bias[j]
// Pass 1: binarize x, W to int8 (+1/-1) in d_ws.
// Pass 2: i8 MFMA GEMM (m97 structure: 128x128 tile, BK=64, global_load_lds w=16,
//         both-sides XOR swizzle on 16B slots, 2-phase double buffer, XCD swizzle).
// Exact: products are +-1, sums are ints <= 2048 -> fp32-exact vs reference.

#define Mdim 16384
#define Ndim 2048
#define Kdim 2048
#define BK 64

using i32x4 = __attribute__((ext_vector_type(4))) int;

__global__ __launch_bounds__(256) void binarize16(const float* __restrict__ in,
                                                  int8_t* __restrict__ out, int n16) {
  int i = blockIdx.x * 256 + threadIdx.x;
  if (i >= n16) return;
  const float4* p = (const float4*)in + (size_t)i * 4;
  float4 f0 = p[0], f1 = p[1], f2 = p[2], f3 = p[3];
  float s[16] = {f0.x, f0.y, f0.z, f0.w, f1.x, f1.y, f1.z, f1.w,
                 f2.x, f2.y, f2.z, f2.w, f3.x, f3.y, f3.z, f3.w};
  union {
    int8_t b[16];
    int4 v;
  } u;
#pragma unroll
  for (int j = 0; j < 16; ++j) u.b[j] = s[j] > 0.0f ? (int8_t)1 : (int8_t)-1;
  ((int4*)out)[i] = u.v;
}

__device__ __forceinline__ void gl_lds16(const void* gsrc, void* ldst) {
  __builtin_amdgcn_global_load_lds(
      (const __attribute__((address_space(1))) void*)gsrc,
      (__attribute__((address_space(3))) void*)ldst, 16, 0, 0);
}

__global__ __launch_bounds__(256) void bin_gemm_i8(const int8_t* __restrict__ A,
                                                   const int8_t* __restrict__ W,
                                                   const float* __restrict__ bias,
                                                   float* __restrict__ C) {
  __shared__ __align__(16) int8_t As[2][128 * BK];
  __shared__ __align__(16) int8_t Bs[2][128 * BK];

  const int tid = threadIdx.x;
  const int lane = tid & 63;
  const int wid = tid >> 6;
  const int wr = wid >> 1;  // wave row half (0..1)
  const int wc = wid & 1;   // wave col half (0..1)

  // XCD-aware swizzle: 2048 blocks, 2048 % 8 == 0 -> simple form is bijective.
  const int nwg = gridDim.x;
  const int cpx = nwg >> 3;
  const int bid = blockIdx.x;
  const int swz = (bid & 7) * cpx + (bid >> 3);
  const int tm = swz >> 4;  // 128 row tiles
  const int tn = swz & 15;  // 16 col tiles
  const long brow = (long)tm * 128;
  const long bcol = (long)tn * 128;

  // ---- staging (global -> LDS, linear dest; swizzle applied to SOURCE addr) ----
  // Per inst q in {0,1}: row_local = q*64 + tid/4, 16B slot s_lin = tid%3..
  // LDS linear slot (row, s_lin) receives global slot (s_lin ^ f(row)), f(row)=(row>>1)&3.
  const int srow = tid >> 2;               // 0..63
  const int slin = tid & 3;                // 16B slot
  const int sf = (tid >> 3) & 3;           // f(row_local) (q*64 doesn't affect bits 1..2)
  const int scol = (slin ^ sf) * 16;       // swizzled byte offset within 64B row chunk

  const int8_t* aSrc0 = A + (brow + srow) * (long)Kdim + scol;
  const int8_t* aSrc1 = A + (brow + 64 + srow) * (long)Kdim + scol;
  const int8_t* bSrc0 = W + (bcol + srow) * (long)Kdim + scol;
  const int8_t* bSrc1 = W + (bcol + 64 + srow) * (long)Kdim + scol;
  const int ldsStageOff = wid * 1024;  // HW adds lane*16

  // ---- fragment ds_read byte offsets (swizzled read: same involution) ----
  int offA[4], offB[4];
#pragma unroll
  for (int m = 0; m < 4; ++m) {
    const int s = lane >> 4;  // k-slot
    const int ra = wr * 64 + m * 16 + (lane & 15);
    offA[m] = ra * 64 + ((s ^ ((ra >> 1) & 3)) * 16);
    const int rb = wc * 64 + m * 16 + (lane & 15);
    offB[m] = rb * 64 + ((s ^ ((rb >> 1) & 3)) * 16);
  }

  i32x4 acc[4][4] = {};

  // prologue: stage t=0 into buf 0
  {
    gl_lds16(aSrc0, &As[0][0 + ldsStageOff]);
    gl_lds16(aSrc1, &As[0][4096 + ldsStageOff]);
    gl_lds16(bSrc0, &Bs[0][0 + ldsStageOff]);
    gl_lds16(bSrc1, &Bs[0][4096 + ldsStageOff]);
  }
  __syncthreads();

  const int NT = Kdim / BK;  // 32
  int cur = 0;
#pragma unroll 1
  for (int t = 0; t < NT; ++t) {
    if (t + 1 < NT) {
      const int kt = (t + 1) * BK;
      const int nxt = cur ^ 1;
      gl_lds16(aSrc0 + kt, &As[nxt][0 + ldsStageOff]);
      gl_lds16(aSrc1 + kt, &As[nxt][4096 + ldsStageOff]);
      gl_lds16(bSrc0 + kt, &Bs[nxt][0 + ldsStageOff]);
      gl_lds16(bSrc1 + kt, &Bs[nxt][4096 + ldsStageOff]);
    }
    i32x4 a[4], b[4];
#pragma unroll
    for (int m = 0; m < 4; ++m) a[m] = *(const i32x4*)&As[cur][offA[m]];
#pragma unroll
    for (int n = 0; n < 4; ++n) b[n] = *(const i32x4*)&Bs[cur][offB[n]];
#pragma unroll
    for (int m = 0; m < 4; ++m)
#pragma unroll
      for (int n = 0; n < 4; ++n)
        acc[m][n] = __builtin_amdgcn_mfma_i32_16x16x64_i8(a[m], b[n], acc[m][n], 0, 0, 0);
    __syncthreads();  // drains vmcnt (staged buffer ready) + lgkm; guards buffer reuse
    cur ^= 1;
  }

  // ---- epilogue: C/D layout col=lane&15, row=(lane>>4)*4+reg ----
#pragma unroll
  for (int n = 0; n < 4; ++n) {
    const long j = bcol + wc * 64 + n * 16 + (lane & 15);
    const float bj = bias[j];
#pragma unroll
    for (int m = 0; m < 4; ++m) {
      const long i0 = brow + wr * 64 + m * 16 + (lane >> 4) * 4;
#pragma unroll
      for (int r = 0; r < 4; ++r) {
        C[(i0 + r) * (long)Ndim + j] = (float)acc[m][n][r] + bj;
      }
    }
  }
}

extern "C" void kernel_launch(void* const* d_in, const int* in_sizes, int n_in,
                              void* d_out, int out_size, void* d_ws, size_t ws_size,
                              hipStream_t stream) {
  const float* x = (const float*)d_in[0];
  const float* w = (const float*)d_in[1];
  const float* bias = (const float*)d_in[2];
  float* out = (float*)d_out;

  int8_t* xb = (int8_t*)d_ws;                       // 33.5 MB
  int8_t* wb = xb + (size_t)Mdim * Kdim;            // + 4.2 MB (needs ws >= 37.8 MB)

  const int nx16 = Mdim * Kdim / 16;  // 2097152
  const int nw16 = Ndim * Kdim / 16;  // 262144
  binarize16<<<nx16 / 256, 256, 0, stream>>>(x, xb, nx16);
  binarize16<<<nw16 / 256, 256, 0, stream>>>(w, wb, nw16);

  dim3 grid((Mdim / 128) * (Ndim / 128));  // 2048, %8==0 for XCD swizzle
  bin_gemm_i8<<<grid, 256, 0, stream>>>(xb, wb, bias, out);
}

// Round 3
// 117.166 us; speedup vs baseline: 1.1722x; 1.1722x over previous
//
#include <hip/hip_runtime.h>
#include <stdint.h>

// BinarizeLinear: out[i][j] = sum_k sign(x[i][k]) * sign(W[j][k]) + bias[j]
// Pass 1 (fused): binarize x and W to int8 (+1/-1) in d_ws.
// Pass 2: i8 MFMA GEMM, 256x256 tile, 8-phase schedule (T2 swizzle + T3/T4
//         counted-vmcnt pipeline + T5 setprio), K-tile = 128 i8 elements.
// Race fix (R3): stage schedule phase-shifted so every restage targets a
// region whose last read is >=1 barrier earlier, and no phase stages a
// region it reads. Per-wave outstanding at tile boundary: 2 (t+1 B-h0) +
// 6 (t+2 A-h0/B-h1/A-h1) -> vmcnt(6) retires all of tile t+1.
// Exact: products are +-1, integer sums <= 2048 -> fp32-exact vs reference.

#define Mdim 16384
#define Ndim 2048
#define Kdim 2048
#define NT 16  // K-tiles of 128 elements

using i32x4 = __attribute__((ext_vector_type(4))) int;

__global__ __launch_bounds__(256) void binarize_both(const float* __restrict__ x,
                                                     const float* __restrict__ w,
                                                     int8_t* __restrict__ out,
                                                     int nx16, int ntot16) {
  int i = blockIdx.x * 256 + threadIdx.x;
  if (i >= ntot16) return;
  const float4* p = (i < nx16) ? ((const float4*)x + (size_t)i * 4)
                               : ((const float4*)w + (size_t)(i - nx16) * 4);
  float4 f0 = p[0], f1 = p[1], f2 = p[2], f3 = p[3];
  float s[16] = {f0.x, f0.y, f0.z, f0.w, f1.x, f1.y, f1.z, f1.w,
                 f2.x, f2.y, f2.z, f2.w, f3.x, f3.y, f3.z, f3.w};
  union { int8_t b[16]; int4 v; } u;
#pragma unroll
  for (int j = 0; j < 16; ++j) u.b[j] = s[j] > 0.0f ? (int8_t)1 : (int8_t)-1;
  ((int4*)out)[i] = u.v;  // xb then wb, contiguous (wb = out + nx16*16)
}

__device__ __forceinline__ void gl_lds16(const void* gsrc, void* ldst) {
  __builtin_amdgcn_global_load_lds(
      (const __attribute__((address_space(1))) void*)gsrc,
      (__attribute__((address_space(3))) void*)ldst, 16, 0, 0);
}

// 8-phase 256^2 i8 GEMM. 512 threads = 8 waves (2M x 4N).
__global__ __launch_bounds__(512, 1) void bin_gemm_i8_8ph(const int8_t* __restrict__ A,
                                                          const int8_t* __restrict__ W,
                                                          const float* __restrict__ bias,
                                                          float* __restrict__ C) {
  // [dbuf][half][128 rows][128 B]; 64 KiB per matrix, 128 KiB total.
  __shared__ __align__(16) int8_t As[2][2][128 * 128];
  __shared__ __align__(16) int8_t Bs[2][2][128 * 128];

  const int tid = threadIdx.x;
  const int lane = tid & 63;
  const int wid = tid >> 6;  // 0..7
  const int wm = wid >> 2;   // 0..1
  const int wn = wid & 3;    // 0..3

  // XCD swizzle: 512 blocks, 512 % 8 == 0 -> simple form bijective.
  const int bid = blockIdx.x;
  const int swz = (bid & 7) * 64 + (bid >> 3);
  const long brow = (long)(swz >> 3) * 256;  // 64 row-tiles
  const long bcol = (long)(swz & 7) * 256;   // 8 col-tiles

  // ---- staging geometry: per wave, per gl_lds q: rows wid*16+q*8 .. +7 ----
  // LDS dest is linear (base + lane*16); swizzle applied to global SOURCE slot.
  const int srow = wid * 16 + (lane >> 3);            // q=0 row-in-half (q=1: +8)
  const int sgcol = ((lane & 7) ^ (lane >> 3)) * 16;  // slot ^ (row&7), same both q

  // ---- ds_read byte offsets (swizzled read: slot ^ (row&7)) ----
  int offA[4][2], offB[2][2];
#pragma unroll
  for (int fr = 0; fr < 4; ++fr) {
    const int ra = wm * 64 + fr * 16 + (lane & 15);
#pragma unroll
    for (int ksl = 0; ksl < 2; ++ksl) {
      const int s = ksl * 4 + (lane >> 4);
      offA[fr][ksl] = ra * 128 + ((s ^ (ra & 7)) * 16);
    }
  }
#pragma unroll
  for (int fc = 0; fc < 2; ++fc) {
    const int rb = wn * 32 + fc * 16 + (lane & 15);
#pragma unroll
    for (int ksl = 0; ksl < 2; ++ksl) {
      const int s = ksl * 4 + (lane >> 4);
      offB[fc][ksl] = rb * 128 + ((s ^ (rb & 7)) * 16);
    }
  }

  i32x4 acc[2][4][2][2] = {};  // [mh][fr][nh][fc]
  i32x4 a[4][2];               // current-mh A frags
  i32x4 b[2][2];               // current-nh B frags

#define STAGE_A(DB, H, KT)                                                              \
  do {                                                                                  \
    const int8_t* s0_ = A + (brow + (H)*128 + srow) * (long)Kdim + (long)(KT)*128 + sgcol; \
    gl_lds16(s0_, &As[DB][H][(wid * 16 + 0) * 128]);                                    \
    gl_lds16(s0_ + (long)8 * Kdim, &As[DB][H][(wid * 16 + 8) * 128]);                   \
  } while (0)
#define STAGE_B(DB, H, KT)                                                              \
  do {                                                                                  \
    const int8_t* s0_ = W + (bcol + (H)*128 + srow) * (long)Kdim + (long)(KT)*128 + sgcol; \
    gl_lds16(s0_, &Bs[DB][H][(wid * 16 + 0) * 128]);                                    \
    gl_lds16(s0_ + (long)8 * Kdim, &Bs[DB][H][(wid * 16 + 8) * 128]);                   \
  } while (0)
#define LOAD_A(DB, H)                                        \
  _Pragma("unroll") for (int fr = 0; fr < 4; ++fr)           \
  _Pragma("unroll") for (int ksl = 0; ksl < 2; ++ksl)        \
      a[fr][ksl] = *(const i32x4*)&As[DB][H][offA[fr][ksl]];
#define LOAD_B(DB, H)                                        \
  _Pragma("unroll") for (int fc = 0; fc < 2; ++fc)           \
  _Pragma("unroll") for (int ksl = 0; ksl < 2; ++ksl)        \
      b[fc][ksl] = *(const i32x4*)&Bs[DB][H][offB[fc][ksl]];
#define MFMA16(MH, NH)                                                        \
  __builtin_amdgcn_s_setprio(1);                                              \
  _Pragma("unroll") for (int fr = 0; fr < 4; ++fr)                            \
  _Pragma("unroll") for (int fc = 0; fc < 2; ++fc)                            \
  _Pragma("unroll") for (int ksl = 0; ksl < 2; ++ksl)                         \
      acc[MH][fr][NH][fc] = __builtin_amdgcn_mfma_i32_16x16x64_i8(            \
          a[fr][ksl], b[fc][ksl], acc[MH][fr][NH][fc], 0, 0, 0);              \
  __builtin_amdgcn_s_setprio(0);
#define SYNC_PRE()                                     \
  __builtin_amdgcn_s_barrier();                        \
  asm volatile("s_waitcnt lgkmcnt(0)" ::: "memory");   \
  __builtin_amdgcn_sched_barrier(0)

  // ---- prologue: tile 0 full (8 loads) + tile 1 A-h0/B-h1/A-h1 (6 loads).
  // Tile 1's B-h0 is staged in iter-0 P1. vmcnt(6) -> tile 0 resident.
  STAGE_A(0, 0, 0); STAGE_A(0, 1, 0); STAGE_B(0, 0, 0); STAGE_B(0, 1, 0);
  STAGE_A(1, 0, 1); STAGE_B(1, 1, 1); STAGE_A(1, 1, 1);
  asm volatile("s_waitcnt vmcnt(6)" ::: "memory");
  __builtin_amdgcn_s_barrier();

#pragma unroll 1
  for (int t = 0; t < NT; ++t) {
    const int db = t & 1;
    const bool pf1 = (t + 1 < NT);
    const bool pf2 = (t + 2 < NT);

    // P1: reads A-h0 + B-h0 (dbuf db); stage B-h0(t+1) -> Bs[db^1][0]
    //     (last read of Bs[db^1][0] was iter t-1 P4 — barrier-separated)
    LOAD_A(db, 0);
    LOAD_B(db, 0);
    if (pf1) STAGE_B(db ^ 1, 0, t + 1);
    SYNC_PRE();
    MFMA16(0, 0);
    __builtin_amdgcn_s_barrier();

    // P2: reads B-h1; stage A-h0(t+2) -> As[db][0] (last read: P1)
    LOAD_B(db, 1);
    if (pf2) STAGE_A(db, 0, t + 2);
    SYNC_PRE();
    MFMA16(0, 1);
    __builtin_amdgcn_s_barrier();

    // P3: reads A-h1; stage B-h1(t+2) -> Bs[db][1] (last read: P2)
    LOAD_A(db, 1);
    if (pf2) STAGE_B(db, 1, t + 2);
    SYNC_PRE();
    MFMA16(1, 1);
    __builtin_amdgcn_s_barrier();

    // P4: re-reads B-h0; stage A-h1(t+2) -> As[db][1] (last read: P3)
    LOAD_B(db, 0);
    if (pf2) STAGE_A(db, 1, t + 2);
    SYNC_PRE();
    MFMA16(1, 0);
    // Boundary: newest 6 outstanding = tile t+2 (P2-P4); everything older
    // (incl. P1's tile t+1 B-h0) retired by vmcnt(6) -> tile t+1 resident.
    if (t < NT - 2) {
      asm volatile("s_waitcnt vmcnt(6)" ::: "memory");
    } else {
      asm volatile("s_waitcnt vmcnt(0)" ::: "memory");
    }
    __builtin_amdgcn_s_barrier();
  }

  // ---- epilogue: C/D layout col=lane&15, row=(lane>>4)*4+reg ----
#pragma unroll
  for (int nh = 0; nh < 2; ++nh) {
#pragma unroll
    for (int fc = 0; fc < 2; ++fc) {
      const long col = bcol + nh * 128 + wn * 32 + fc * 16 + (lane & 15);
      const float bj = bias[col];
#pragma unroll
      for (int mh = 0; mh < 2; ++mh) {
#pragma unroll
        for (int fr = 0; fr < 4; ++fr) {
          const long row0 = brow + mh * 128 + wm * 64 + fr * 16 + (lane >> 4) * 4;
#pragma unroll
          for (int r = 0; r < 4; ++r) {
            C[(row0 + r) * (long)Ndim + col] = (float)acc[mh][fr][nh][fc][r] + bj;
          }
        }
      }
    }
  }
#undef STAGE_A
#undef STAGE_B
#undef LOAD_A
#undef LOAD_B
#undef MFMA16
#undef SYNC_PRE
}

extern "C" void kernel_launch(void* const* d_in, const int* in_sizes, int n_in,
                              void* d_out, int out_size, void* d_ws, size_t ws_size,
                              hipStream_t stream) {
  const float* x = (const float*)d_in[0];
  const float* w = (const float*)d_in[1];
  const float* bias = (const float*)d_in[2];
  float* out = (float*)d_out;

  int8_t* xb = (int8_t*)d_ws;             // 33.5 MB
  int8_t* wb = xb + (size_t)Mdim * Kdim;  // + 4.2 MB (ws >= 37.8 MB)

  const int nx16 = Mdim * Kdim / 16;
  const int nw16 = Ndim * Kdim / 16;
  const int ntot16 = nx16 + nw16;
  binarize_both<<<(ntot16 + 255) / 256, 256, 0, stream>>>(x, w, xb, nx16, ntot16);

  dim3 grid((Mdim / 256) * (Ndim / 256));  // 512 blocks, %8==0
  bin_gemm_i8_8ph<<<grid, 512, 0, stream>>>(xb, wb, bias, out);
}

// Round 4
// 115.777 us; speedup vs baseline: 1.1863x; 1.0120x over previous
//
#include <hip/hip_runtime.h>
#include <stdint.h>

// BinarizeLinear: out[i][j] = sum_k sign(x[i][k]) * sign(W[j][k]) + bias[j]
// Pass 1 (fused): binarize x and W to int8 (+1/-1) in d_ws.
// Pass 2: i8 MFMA GEMM, 256x256 tile, 8-phase counted-vmcnt schedule.
// R4: persistent blocks (grid=256, 2 adjacent M-tiles per block, continuous
// 32-iter K-loop with cross-tile prefetch; mid epilogue overlapped with
// tile-2 phases) + B-h0 fragments held in regs (P4 has no ds_reads).
// Ledger: P1 stages B-h0(u+1)->Bs[db^1][0] (last read prev-u P1);
//         P2 A-h0(u+2)->As[db][0] (last read P1); P3 B-h1(u+2)->Bs[db][1]
//         (last read P2); P4 A-h1(u+2)->As[db][1] (last read P3).
// Boundary vmcnt(6): newest 6 = tile u+2 stages -> tile u+1 resident.
// Exact: products are +-1, integer sums <= 2048 -> fp32-exact vs reference.

#define Mdim 16384
#define Ndim 2048
#define Kdim 2048
#define NT 16  // K-tiles of 128 i8 per M-tile
#define NU 32  // 2 M-tiles x NT, continuous iteration space

using i32x4 = __attribute__((ext_vector_type(4))) int;

__global__ __launch_bounds__(256) void binarize_both(const float* __restrict__ x,
                                                     const float* __restrict__ w,
                                                     int8_t* __restrict__ out,
                                                     int nx16, int ntot16) {
  int i = blockIdx.x * 256 + threadIdx.x;
  if (i >= ntot16) return;
  const float4* p = (i < nx16) ? ((const float4*)x + (size_t)i * 4)
                               : ((const float4*)w + (size_t)(i - nx16) * 4);
  float4 f0 = p[0], f1 = p[1], f2 = p[2], f3 = p[3];
  float s[16] = {f0.x, f0.y, f0.z, f0.w, f1.x, f1.y, f1.z, f1.w,
                 f2.x, f2.y, f2.z, f2.w, f3.x, f3.y, f3.z, f3.w};
  union { int8_t b[16]; int4 v; } u;
#pragma unroll
  for (int j = 0; j < 16; ++j) u.b[j] = s[j] > 0.0f ? (int8_t)1 : (int8_t)-1;
  ((int4*)out)[i] = u.v;  // xb then wb, contiguous (wb = out + nx16*16)
}

__device__ __forceinline__ void gl_lds16(const void* gsrc, void* ldst) {
  __builtin_amdgcn_global_load_lds(
      (const __attribute__((address_space(1))) void*)gsrc,
      (__attribute__((address_space(3))) void*)ldst, 16, 0, 0);
}

__global__ __launch_bounds__(512, 2) void bin_gemm_i8_8ph(const int8_t* __restrict__ A,
                                                          const int8_t* __restrict__ W,
                                                          const float* __restrict__ bias,
                                                          float* __restrict__ C) {
  // [dbuf][half][128 rows][128 B]; 64 KiB per matrix, 128 KiB total.
  __shared__ __align__(16) int8_t As[2][2][128 * 128];
  __shared__ __align__(16) int8_t Bs[2][2][128 * 128];

  const int tid = threadIdx.x;
  const int lane = tid & 63;
  const int wid = tid >> 6;  // 0..7
  const int wm = wid >> 2;   // 0..1
  const int wn = wid & 3;    // 0..3

  // XCD swizzle: 256 blocks, cpx=32, bijective. swz -> (row-pair, col-tile).
  const int bid = blockIdx.x;
  const int swz = (bid & 7) * 32 + (bid >> 3);
  const long brow = (long)(swz >> 3) * 512;  // 32 row-pairs (2 x 256 rows each)
  const long bcol = (long)(swz & 7) * 256;   // 8 col-tiles

  // ---- staging geometry: per wave, per gl_lds q: rows wid*16+q*8 .. +7 ----
  // LDS dest linear (base + lane*16); swizzle applied to global SOURCE slot.
  const int srow = wid * 16 + (lane >> 3);            // q=0 row-in-half (q=1: +8)
  const int sgcol = ((lane & 7) ^ (lane >> 3)) * 16;  // slot ^ (row&7)

  // ---- ds_read byte offsets (swizzled read: slot ^ (row&7)) ----
  int offA[4][2], offB[2][2];
#pragma unroll
  for (int fr = 0; fr < 4; ++fr) {
    const int ra = wm * 64 + fr * 16 + (lane & 15);
#pragma unroll
    for (int ksl = 0; ksl < 2; ++ksl) {
      const int s = ksl * 4 + (lane >> 4);
      offA[fr][ksl] = ra * 128 + ((s ^ (ra & 7)) * 16);
    }
  }
#pragma unroll
  for (int fc = 0; fc < 2; ++fc) {
    const int rb = wn * 32 + fc * 16 + (lane & 15);
#pragma unroll
    for (int ksl = 0; ksl < 2; ++ksl) {
      const int s = ksl * 4 + (lane >> 4);
      offB[fc][ksl] = rb * 128 + ((s ^ (rb & 7)) * 16);
    }
  }

  i32x4 acc[2][4][2][2] = {};  // [mh][fr][nh][fc]
  i32x4 a[4][2];               // current-mh A frags
  i32x4 b0[2][2], b1[2][2];    // B-h0 held P1..P4; B-h1 held P2..P3

  // Staged tile V: M-tile = V>>4 (row base +256 per), kt = V&15, dbuf = V&1.
#define STAGE_A(DB, H, V)                                                          \
  do {                                                                             \
    const long mb_ = brow + ((long)((V) >> 4) << 8);                               \
    const int8_t* s0_ =                                                            \
        A + (mb_ + (H)*128 + srow) * (long)Kdim + ((long)((V)&15) << 7) + sgcol;   \
    gl_lds16(s0_, &As[DB][H][(wid * 16 + 0) * 128]);                               \
    gl_lds16(s0_ + (long)8 * Kdim, &As[DB][H][(wid * 16 + 8) * 128]);              \
  } while (0)
#define STAGE_B(DB, H, V)                                                          \
  do {                                                                             \
    const int8_t* s0_ =                                                            \
        W + (bcol + (H)*128 + srow) * (long)Kdim + ((long)((V)&15) << 7) + sgcol;  \
    gl_lds16(s0_, &Bs[DB][H][(wid * 16 + 0) * 128]);                               \
    gl_lds16(s0_ + (long)8 * Kdim, &Bs[DB][H][(wid * 16 + 8) * 128]);              \
  } while (0)
#define LOAD_A(DB, H)                                        \
  _Pragma("unroll") for (int fr = 0; fr < 4; ++fr)           \
  _Pragma("unroll") for (int ksl = 0; ksl < 2; ++ksl)        \
      a[fr][ksl] = *(const i32x4*)&As[DB][H][offA[fr][ksl]];
#define LOAD_B(DB, H, BB)                                    \
  _Pragma("unroll") for (int fc = 0; fc < 2; ++fc)           \
  _Pragma("unroll") for (int ksl = 0; ksl < 2; ++ksl)        \
      BB[fc][ksl] = *(const i32x4*)&Bs[DB][H][offB[fc][ksl]];
#define MFMA16(MH, NH, BB)                                                    \
  __builtin_amdgcn_s_setprio(1);                                              \
  _Pragma("unroll") for (int fr = 0; fr < 4; ++fr)                            \
  _Pragma("unroll") for (int fc = 0; fc < 2; ++fc)                            \
  _Pragma("unroll") for (int ksl = 0; ksl < 2; ++ksl)                         \
      acc[MH][fr][NH][fc] = __builtin_amdgcn_mfma_i32_16x16x64_i8(            \
          a[fr][ksl], BB[fc][ksl], acc[MH][fr][NH][fc], 0, 0, 0);             \
  __builtin_amdgcn_s_setprio(0);
#define SYNC_PRE()                                     \
  __builtin_amdgcn_s_barrier();                        \
  asm volatile("s_waitcnt lgkmcnt(0)" ::: "memory");   \
  __builtin_amdgcn_sched_barrier(0)

  // ---- prologue: tile 0 full (8 loads) + tile 1 A-h0/B-h1/A-h1 (6 loads).
  STAGE_A(0, 0, 0); STAGE_A(0, 1, 0); STAGE_B(0, 0, 0); STAGE_B(0, 1, 0);
  STAGE_A(1, 0, 1); STAGE_B(1, 1, 1); STAGE_A(1, 1, 1);
  asm volatile("s_waitcnt vmcnt(6)" ::: "memory");
  __builtin_amdgcn_s_barrier();

#pragma unroll 1
  for (int mt = 0; mt < 2; ++mt) {
#pragma unroll 1
    for (int tt = 0; tt < NT; ++tt) {
      const int u = (mt << 4) | tt;
      const int db = u & 1;
      const bool pf1 = (u + 1 < NU);
      const bool pf2 = (u + 2 < NU);

      // P1: reads A-h0 + B-h0->b0; stage B-h0(u+1) (last read: prev-u P1)
      LOAD_A(db, 0);
      LOAD_B(db, 0, b0);
      if (pf1) STAGE_B(db ^ 1, 0, u + 1);
      SYNC_PRE();
      MFMA16(0, 0, b0);
      __builtin_amdgcn_s_barrier();

      // P2: reads B-h1->b1; stage A-h0(u+2) (last read: P1)
      LOAD_B(db, 1, b1);
      if (pf2) STAGE_A(db, 0, u + 2);
      SYNC_PRE();
      MFMA16(0, 1, b1);
      __builtin_amdgcn_s_barrier();

      // P3: reads A-h1; stage B-h1(u+2) (last read: P2)
      LOAD_A(db, 1);
      if (pf2) STAGE_B(db, 1, u + 2);
      SYNC_PRE();
      MFMA16(1, 1, b1);
      __builtin_amdgcn_s_barrier();

      // P4: no LDS reads (b0 held from P1); stage A-h1(u+2) (last read: P3)
      if (pf2) STAGE_A(db, 1, u + 2);
      SYNC_PRE();
      MFMA16(1, 0, b0);
      if (u < NU - 2) {
        asm volatile("s_waitcnt vmcnt(6)" ::: "memory");
      } else {
        asm volatile("s_waitcnt vmcnt(0)" ::: "memory");
      }
      __builtin_amdgcn_s_barrier();
    }

    // ---- epilogue for M-tile mt. For mt=0 the stores drain under tile-2's
    // phases (later vmcnt(6) waits are conservative w.r.t. these older stores).
    {
      const long mbase = brow + ((long)mt << 8);
#pragma unroll
      for (int nh = 0; nh < 2; ++nh) {
#pragma unroll
        for (int fc = 0; fc < 2; ++fc) {
          const long col = bcol + nh * 128 + wn * 32 + fc * 16 + (lane & 15);
          const float bj = bias[col];
#pragma unroll
          for (int mh = 0; mh < 2; ++mh) {
#pragma unroll
            for (int fr = 0; fr < 4; ++fr) {
              const long row0 = mbase + mh * 128 + wm * 64 + fr * 16 + (lane >> 4) * 4;
#pragma unroll
              for (int r = 0; r < 4; ++r) {
                C[(row0 + r) * (long)Ndim + col] = (float)acc[mh][fr][nh][fc][r] + bj;
              }
            }
          }
        }
      }
      if (mt == 0) {
#pragma unroll
        for (int mh = 0; mh < 2; ++mh)
#pragma unroll
          for (int fr = 0; fr < 4; ++fr)
#pragma unroll
            for (int nh = 0; nh < 2; ++nh)
#pragma unroll
              for (int fc = 0; fc < 2; ++fc) acc[mh][fr][nh][fc] = i32x4{0, 0, 0, 0};
      }
    }
  }
#undef STAGE_A
#undef STAGE_B
#undef LOAD_A
#undef LOAD_B
#undef MFMA16
#undef SYNC_PRE
}

extern "C" void kernel_launch(void* const* d_in, const int* in_sizes, int n_in,
                              void* d_out, int out_size, void* d_ws, size_t ws_size,
                              hipStream_t stream) {
  const float* x = (const float*)d_in[0];
  const float* w = (const float*)d_in[1];
  const float* bias = (const float*)d_in[2];
  float* out = (float*)d_out;

  int8_t* xb = (int8_t*)d_ws;             // 33.5 MB
  int8_t* wb = xb + (size_t)Mdim * Kdim;  // + 4.2 MB (ws >= 37.8 MB)

  const int nx16 = Mdim * Kdim / 16;
  const int nw16 = Ndim * Kdim / 16;
  const int ntot16 = nx16 + nw16;
  binarize_both<<<(ntot16 + 255) / 256, 256, 0, stream>>>(x, w, xb, nx16, ntot16);

  dim3 grid((Mdim / 512) * (Ndim / 256));  // 256 persistent blocks, %8==0
  bin_gemm_i8_8ph<<<grid, 512, 0, stream>>>(xb, wb, bias, out);
}